// Round 11
// baseline (782.234 us; speedup 1.0000x reference)
//
#include <hip/hip_runtime.h>
#include <hip/hip_bf16.h>
#include <math.h>

// BoxE scorer:
//   y: (2048, 256) f32 -> boxes: mn = y[:, :128], delta = softplus(y[:, 128:])
//   x: (1024, 128) f32 -> points
//   out[m][n] = -|| per_dim(x[m], box[n]) ||_2, shape (1024, 2048) f32
//
// R10: R9 showed VGPR_Count=16 — launch_bounds(256,8) starved the allocator,
// serializing the per-k p4 loads on ~200cyc L2 latency (issue-slot util ~31%;
// VALUBusy 71% is the gfx94x 2x-inflated formula). Fix: launch_bounds(256,4)
// + explicit 8-deep register prefetch ring for p4 (static indices via nested
// unrolled loops; p4 padded +8 k-rows so the tail prefetch reads harmless
// poison that is never consumed).

#define BM 16
#define BN 64
#define TM 4
#define XPAD 20   // floats per xtile row: 16 data + 4 pad (80B, 16B-aligned)
#define PF 8      // prefetch depth (k-rows ahead)

// ---- prep: y (2048,256) -> p4[k][n] = {center, hd, inv, c2}, [128][2048] ----
__global__ __launch_bounds__(256) void boxe_prep(const float* __restrict__ y,
                                                 float4* __restrict__ p4)
{
    __shared__ float t0[128][9], t1[128][9], t2[128][9], t3[128][9];
    const int tid = threadIdx.x;
    const int n0  = blockIdx.x * 8;

    // phase 1: k-fastest mapping -> coalesced y reads (256B/wave)
#pragma unroll
    for (int i = 0; i < 4; ++i) {
        int j  = i * 256 + tid;        // 0..1023 = 8 n x 128 k
        int k  = j & 127;
        int nl = j >> 7;
        int n  = n0 + nl;
        float mn = y[n * 256 + k];
        float dv = y[n * 256 + 128 + k];
        // stable softplus: max(v,0) + log1p(exp(-|v|))  (matches jax.nn.softplus)
        float delta = fmaxf(dv, 0.0f) + log1pf(expf(-fabsf(dv)));
        float hd  = 0.5f * delta;
        t0[k][nl] = mn + hd;                                // center
        t1[k][nl] = hd;                                     // half-width
        t2[k][nl] = 1.0f / (delta + 1.0f + 1e-10f);         // 1/(dp1+eps)
        t3[k][nl] = hd * (delta - 1.0f / (delta + 1e-10f)); // c2
    }
    __syncthreads();

    // phase 2: n-fastest mapping -> coalesced p4 writes
#pragma unroll
    for (int i = 0; i < 4; ++i) {
        int j  = i * 256 + tid;
        int nl = j & 7;
        int k  = j >> 3;
        p4[k * 2048 + n0 + nl] =
            make_float4(t0[k][nl], t1[k][nl], t2[k][nl], t3[k][nl]);
    }
}

// ---- main: out[m][n] = -sqrt( sum_k per_dim^2 ) ----
__global__ __launch_bounds__(256, 4) void boxe_main(
    const float4* __restrict__ p4, const float* __restrict__ x,
    float* __restrict__ out)
{
    __shared__ float xtile[128][XPAD];   // 10.24 KiB

    const int tid  = threadIdx.x;
    const int lane = tid & 63;
    const int wave = tid >> 6;
    const int m0   = blockIdx.y * BM;
    const int n0   = blockIdx.x * BN;

    // Stage x tile: 16 m x 128 k, k-fastest -> coalesced 256B/wave reads.
#pragma unroll
    for (int i = 0; i < (128 * BM) / 256; ++i) {
        int idx = i * 256 + tid;       // 16 m x 128 k
        int m = idx >> 7;
        int k = idx & 127;
        xtile[k][m] = x[(m0 + m) * 128 + k];
    }
    __syncthreads();

    float acc[TM];
#pragma unroll
    for (int r = 0; r < TM; ++r) acc[r] = 0.0f;

    const int n  = n0 + lane;     // one box per lane, coalesced float4 loads
    const int mw = wave * TM;     // this wave's m-offset (0,4,8,12), 16B-aligned

    // 8-deep register prefetch ring for p4 (static indexing only).
    float4 pbuf[PF];
#pragma unroll
    for (int i = 0; i < PF; ++i) pbuf[i] = p4[i * 2048 + n];

    for (int ko = 0; ko < 128 / PF; ++ko) {
#pragma unroll
        for (int ki = 0; ki < PF; ++ki) {
            const int k = ko * PF + ki;
            float4 p = pbuf[ki];
            // prefetch k+PF; rows 128..135 are padded poison, never consumed
            pbuf[ki] = p4[(k + PF) * 2048 + n];
            float4 xv = *(const float4*)&xtile[k][mw];      // ds_read_b128
            float dp1 = fmaf(2.0f, p.y, 1.0f);              // delta+1, exact
#pragma unroll
            for (int r = 0; r < TM; ++r) {
                float xr = (r == 0) ? xv.x : (r == 1) ? xv.y
                         : (r == 2) ? xv.z : xv.w;
                float l = fabsf(xr - p.x);
                float v = (l <= p.y) ? (l * p.z) : fmaf(l, dp1, -p.w);
                acc[r] = fmaf(v, v, acc[r]);
            }
        }
    }

#pragma unroll
    for (int r = 0; r < TM; ++r) {
        int m = m0 + mw + r;
        out[m * 2048 + n] = -sqrtf(acc[r]);
    }
}

extern "C" void kernel_launch(void* const* d_in, const int* in_sizes, int n_in,
                              void* d_out, int out_size, void* d_ws, size_t ws_size,
                              hipStream_t stream) {
    const float* y = (const float*)d_in[0];   // 2048*256
    const float* x = (const float*)d_in[1];   // 1024*128
    float* out = (float*)d_out;               // 1024*2048

    // p4: [128+PF][2048] float4 = 4.25 MiB; last PF rows stay harness-poisoned
    // (read by the tail prefetch, never consumed in arithmetic).
    float4* p4 = (float4*)d_ws;

    hipLaunchKernelGGL(boxe_prep, dim3(2048 / 8), dim3(256), 0, stream, y, p4);

    dim3 grid(2048 / BN, 1024 / BM);          // (32, 64) = 2048 blocks
    hipLaunchKernelGGL(boxe_main, grid, dim3(256), 0, stream, p4, x, out);
}

// Round 12
// 261.511 us; speedup vs baseline: 2.9912x; 2.9912x over previous
//
#include <hip/hip_runtime.h>
#include <hip/hip_bf16.h>
#include <math.h>

// BoxE scorer:
//   y: (2048, 256) f32 -> boxes: mn = y[:, :128], delta = softplus(y[:, 128:])
//   x: (1024, 128) f32 -> points
//   out[m][n] = -|| per_dim(x[m], box[n]) ||_2, shape (1024, 2048) f32
//
// R12: R11's pbuf[8] array went to SCRATCH (WRITE_SIZE 1.4GB, FETCH 837MB =
// spill traffic; rule #20 — compiler didn't keep the ring in regs). Rewritten
// with 8 NAMED float4 registers a0..a7, hand-unrolled 8-step software
// pipeline: consume a_j at k=kb+j, reload a_j from row kb+8+j. Named SSA
// values can't be spilled as an array; each load has ~8 steps (~400cy) of
// independent VALU before its use -> L2 latency hidden via counted vmcnt.

#define BM 16
#define BN 64
#define TM 4
#define XPAD 20   // floats per xtile row: 16 data + 4 pad (80B, 16B-aligned)

// ---- prep: y (2048,256) -> p4[k][n] = {center, hd, inv, c2}, [128][2048] ----
__global__ __launch_bounds__(256) void boxe_prep(const float* __restrict__ y,
                                                 float4* __restrict__ p4)
{
    __shared__ float t0[128][9], t1[128][9], t2[128][9], t3[128][9];
    const int tid = threadIdx.x;
    const int n0  = blockIdx.x * 8;

    // phase 1: k-fastest mapping -> coalesced y reads (256B/wave)
#pragma unroll
    for (int i = 0; i < 4; ++i) {
        int j  = i * 256 + tid;        // 0..1023 = 8 n x 128 k
        int k  = j & 127;
        int nl = j >> 7;
        int n  = n0 + nl;
        float mn = y[n * 256 + k];
        float dv = y[n * 256 + 128 + k];
        // stable softplus: max(v,0) + log1p(exp(-|v|))  (matches jax.nn.softplus)
        float delta = fmaxf(dv, 0.0f) + log1pf(expf(-fabsf(dv)));
        float hd  = 0.5f * delta;
        t0[k][nl] = mn + hd;                                // center
        t1[k][nl] = hd;                                     // half-width
        t2[k][nl] = 1.0f / (delta + 1.0f + 1e-10f);         // 1/(dp1+eps)
        t3[k][nl] = hd * (delta - 1.0f / (delta + 1e-10f)); // c2
    }
    __syncthreads();

    // phase 2: n-fastest mapping -> coalesced p4 writes
#pragma unroll
    for (int i = 0; i < 4; ++i) {
        int j  = i * 256 + tid;
        int nl = j & 7;
        int k  = j >> 3;
        p4[k * 2048 + n0 + nl] =
            make_float4(t0[k][nl], t1[k][nl], t2[k][nl], t3[k][nl]);
    }
}

// ---- main: out[m][n] = -sqrt( sum_k per_dim^2 ) ----
__global__ __launch_bounds__(256, 4) void boxe_main(
    const float4* __restrict__ p4, const float* __restrict__ x,
    float* __restrict__ out)
{
    __shared__ float xtile[128][XPAD];   // 10.24 KiB

    const int tid  = threadIdx.x;
    const int lane = tid & 63;
    const int wave = tid >> 6;
    const int m0   = blockIdx.y * BM;
    const int n0   = blockIdx.x * BN;

    // Stage x tile: 16 m x 128 k, k-fastest -> coalesced 256B/wave reads.
#pragma unroll
    for (int i = 0; i < (128 * BM) / 256; ++i) {
        int idx = i * 256 + tid;       // 16 m x 128 k
        int m = idx >> 7;
        int k = idx & 127;
        xtile[k][m] = x[(m0 + m) * 128 + k];
    }
    __syncthreads();

    float acc0 = 0.0f, acc1 = 0.0f, acc2 = 0.0f, acc3 = 0.0f;

    const int n  = n0 + lane;     // one box per lane, coalesced float4 loads
    const int mw = wave * TM;     // this wave's m-offset (0,4,8,12), 16B-aligned

    // One step: consume params P at k-row KK against the 4 x-values.
#define STEP(P, KK)                                                        \
    do {                                                                   \
        float4 xv = *(const float4*)&xtile[(KK)][mw];  /* ds_read_b128 */  \
        float dp1 = fmaf(2.0f, (P).y, 1.0f);           /* delta+1 exact */ \
        float l0 = fabsf(xv.x - (P).x);                                    \
        float l1 = fabsf(xv.y - (P).x);                                    \
        float l2 = fabsf(xv.z - (P).x);                                    \
        float l3 = fabsf(xv.w - (P).x);                                    \
        float v0 = (l0 <= (P).y) ? (l0 * (P).z) : fmaf(l0, dp1, -(P).w);   \
        float v1 = (l1 <= (P).y) ? (l1 * (P).z) : fmaf(l1, dp1, -(P).w);   \
        float v2 = (l2 <= (P).y) ? (l2 * (P).z) : fmaf(l2, dp1, -(P).w);   \
        float v3 = (l3 <= (P).y) ? (l3 * (P).z) : fmaf(l3, dp1, -(P).w);   \
        acc0 = fmaf(v0, v0, acc0);                                         \
        acc1 = fmaf(v1, v1, acc1);                                         \
        acc2 = fmaf(v2, v2, acc2);                                         \
        acc3 = fmaf(v3, v3, acc3);                                         \
    } while (0)

    // Prologue: rows 0..7 in named registers (8 loads in flight).
    float4 a0 = p4[0 * 2048 + n];
    float4 a1 = p4[1 * 2048 + n];
    float4 a2 = p4[2 * 2048 + n];
    float4 a3 = p4[3 * 2048 + n];
    float4 a4 = p4[4 * 2048 + n];
    float4 a5 = p4[5 * 2048 + n];
    float4 a6 = p4[6 * 2048 + n];
    float4 a7 = p4[7 * 2048 + n];

    // Steady state: consume a_j at kb+j, reload a_j from kb+8+j.
    int kb = 0;
    for (int ko = 0; ko < 15; ++ko, kb += 8) {
        STEP(a0, kb + 0); a0 = p4[(kb +  8) * 2048 + n];
        STEP(a1, kb + 1); a1 = p4[(kb +  9) * 2048 + n];
        STEP(a2, kb + 2); a2 = p4[(kb + 10) * 2048 + n];
        STEP(a3, kb + 3); a3 = p4[(kb + 11) * 2048 + n];
        STEP(a4, kb + 4); a4 = p4[(kb + 12) * 2048 + n];
        STEP(a5, kb + 5); a5 = p4[(kb + 13) * 2048 + n];
        STEP(a6, kb + 6); a6 = p4[(kb + 14) * 2048 + n];
        STEP(a7, kb + 7); a7 = p4[(kb + 15) * 2048 + n];
    }
    // Epilogue: rows 120..127, no reload.
    STEP(a0, 120); STEP(a1, 121); STEP(a2, 122); STEP(a3, 123);
    STEP(a4, 124); STEP(a5, 125); STEP(a6, 126); STEP(a7, 127);
#undef STEP

    out[(m0 + mw + 0) * 2048 + n] = -sqrtf(acc0);
    out[(m0 + mw + 1) * 2048 + n] = -sqrtf(acc1);
    out[(m0 + mw + 2) * 2048 + n] = -sqrtf(acc2);
    out[(m0 + mw + 3) * 2048 + n] = -sqrtf(acc3);
}

extern "C" void kernel_launch(void* const* d_in, const int* in_sizes, int n_in,
                              void* d_out, int out_size, void* d_ws, size_t ws_size,
                              hipStream_t stream) {
    const float* y = (const float*)d_in[0];   // 2048*256
    const float* x = (const float*)d_in[1];   // 1024*128
    float* out = (float*)d_out;               // 1024*2048

    float4* p4 = (float4*)d_ws;               // 4 MiB: [128][2048] float4

    hipLaunchKernelGGL(boxe_prep, dim3(2048 / 8), dim3(256), 0, stream, y, p4);

    dim3 grid(2048 / BN, 1024 / BM);          // (32, 64) = 2048 blocks
    hipLaunchKernelGGL(boxe_main, grid, dim3(256), 0, stream, p4, x, out);
}

// Round 13
// 115.827 us; speedup vs baseline: 6.7535x; 2.2578x over previous
//
#include <hip/hip_runtime.h>
#include <hip/hip_bf16.h>
#include <math.h>

// BoxE scorer:
//   y: (2048, 256) f32 -> boxes: mn = y[:, :128], delta = softplus(y[:, 128:])
//   x: (1024, 128) f32 -> points
//   out[m][n] = -|| per_dim(x[m], box[n]) ||_2, shape (1024, 2048) f32
//
// R13: R6/R9 pinned at ~65us regardless of occupancy -> shared-pipe bound:
// one ds_read_b128 per wave per k-step saturates the LDS pipe (~12cyc each;
// 32 waves/CU x 128 reads = ~20us LDS issue) and lgkmcnt chains serialize.
// Fix: NO LDS in main. x values are wave-uniform -> scalar path: readfirstlane
// makes row pointers uniform, xr[k] compiles to s_load (K$), VALU takes the
// scalar as src0. TM 4->8 (BM 32) halves p4 L2 traffic (537MB, 15.6us floor).
// Compiler-scheduled unroll 8 (merges consecutive-k s_loads into dwordx8).

#define BM 32
#define BN 64
#define TM 8

// ---- prep: y (2048,256) -> p4[k][n] = {center, hd, inv, c2}, [128][2048] ----
__global__ __launch_bounds__(256) void boxe_prep(const float* __restrict__ y,
                                                 float4* __restrict__ p4)
{
    __shared__ float t0[128][9], t1[128][9], t2[128][9], t3[128][9];
    const int tid = threadIdx.x;
    const int n0  = blockIdx.x * 8;

    // phase 1: k-fastest mapping -> coalesced y reads (256B/wave)
#pragma unroll
    for (int i = 0; i < 4; ++i) {
        int j  = i * 256 + tid;        // 0..1023 = 8 n x 128 k
        int k  = j & 127;
        int nl = j >> 7;
        int n  = n0 + nl;
        float mn = y[n * 256 + k];
        float dv = y[n * 256 + 128 + k];
        // stable softplus: max(v,0) + log1p(exp(-|v|))  (matches jax.nn.softplus)
        float delta = fmaxf(dv, 0.0f) + log1pf(expf(-fabsf(dv)));
        float hd  = 0.5f * delta;
        t0[k][nl] = mn + hd;                                // center
        t1[k][nl] = hd;                                     // half-width
        t2[k][nl] = 1.0f / (delta + 1.0f + 1e-10f);         // 1/(dp1+eps)
        t3[k][nl] = hd * (delta - 1.0f / (delta + 1e-10f)); // c2
    }
    __syncthreads();

    // phase 2: n-fastest mapping -> coalesced p4 writes
#pragma unroll
    for (int i = 0; i < 4; ++i) {
        int j  = i * 256 + tid;
        int nl = j & 7;
        int k  = j >> 3;
        p4[k * 2048 + n0 + nl] =
            make_float4(t0[k][nl], t1[k][nl], t2[k][nl], t3[k][nl]);
    }
}

// ---- main: out[m][n] = -sqrt( sum_k per_dim^2 ) ----
// No LDS. Each wave: 8 m-rows (x via scalar loads), 64 n (one per lane).
__global__ __launch_bounds__(256, 4) void boxe_main(
    const float4* __restrict__ p4, const float* __restrict__ x,
    float* __restrict__ out)
{
    const int tid  = threadIdx.x;
    const int lane = tid & 63;
    const int wave = __builtin_amdgcn_readfirstlane(tid >> 6);  // uniform
    const int m0   = blockIdx.y * BM + wave * TM;  // this wave's first m-row
    const int n    = blockIdx.x * BN + lane;       // one box per lane

    // Uniform row pointers -> xr*[k] are scalar (s_load) reads.
    const float* xr0 = x + (m0 + 0) * 128;
    const float* xr1 = x + (m0 + 1) * 128;
    const float* xr2 = x + (m0 + 2) * 128;
    const float* xr3 = x + (m0 + 3) * 128;
    const float* xr4 = x + (m0 + 4) * 128;
    const float* xr5 = x + (m0 + 5) * 128;
    const float* xr6 = x + (m0 + 6) * 128;
    const float* xr7 = x + (m0 + 7) * 128;

    const float4* pp = p4 + n;

    float acc0 = 0.0f, acc1 = 0.0f, acc2 = 0.0f, acc3 = 0.0f;
    float acc4 = 0.0f, acc5 = 0.0f, acc6 = 0.0f, acc7 = 0.0f;

#define EVAL(ACC, XS)                                                     \
    do {                                                                  \
        float l = fabsf((XS) - p.x);                                      \
        float v = (l <= p.y) ? (l * p.z) : fmaf(l, dp1, -p.w);            \
        ACC = fmaf(v, v, ACC);                                            \
    } while (0)

#pragma unroll 8
    for (int k = 0; k < 128; ++k) {
        float4 p  = pp[k * 2048];              // {center, hd, inv, c2}, L2
        float dp1 = fmaf(2.0f, p.y, 1.0f);     // delta+1, exact
        EVAL(acc0, xr0[k]);
        EVAL(acc1, xr1[k]);
        EVAL(acc2, xr2[k]);
        EVAL(acc3, xr3[k]);
        EVAL(acc4, xr4[k]);
        EVAL(acc5, xr5[k]);
        EVAL(acc6, xr6[k]);
        EVAL(acc7, xr7[k]);
    }
#undef EVAL

    out[(m0 + 0) * 2048 + n] = -sqrtf(acc0);
    out[(m0 + 1) * 2048 + n] = -sqrtf(acc1);
    out[(m0 + 2) * 2048 + n] = -sqrtf(acc2);
    out[(m0 + 3) * 2048 + n] = -sqrtf(acc3);
    out[(m0 + 4) * 2048 + n] = -sqrtf(acc4);
    out[(m0 + 5) * 2048 + n] = -sqrtf(acc5);
    out[(m0 + 6) * 2048 + n] = -sqrtf(acc6);
    out[(m0 + 7) * 2048 + n] = -sqrtf(acc7);
}

extern "C" void kernel_launch(void* const* d_in, const int* in_sizes, int n_in,
                              void* d_out, int out_size, void* d_ws, size_t ws_size,
                              hipStream_t stream) {
    const float* y = (const float*)d_in[0];   // 2048*256
    const float* x = (const float*)d_in[1];   // 1024*128
    float* out = (float*)d_out;               // 1024*2048

    float4* p4 = (float4*)d_ws;               // 4 MiB: [128][2048] float4

    hipLaunchKernelGGL(boxe_prep, dim3(2048 / 8), dim3(256), 0, stream, y, p4);

    dim3 grid(2048 / BN, 1024 / BM);          // (32, 32) = 1024 blocks
    hipLaunchKernelGGL(boxe_main, grid, dim3(256), 0, stream, p4, x, out);
}

// Round 15
// 108.963 us; speedup vs baseline: 7.1789x; 1.0630x over previous
//
#include <hip/hip_runtime.h>
#include <hip/hip_bf16.h>
#include <math.h>

// BoxE scorer:
//   y: (2048, 256) f32 -> boxes: mn = y[:, :128], delta = softplus(y[:, 128:])
//   x: (1024, 128) f32 -> points
//   out[m][n] = -|| per_dim(x[m], box[n]) ||_2, shape (1024, 2048) f32
//
// R14: ~63us invariant across R6/R9/R13 (occupancy 35-59%, LDS or no LDS)
// with VGPR_Count 12-24 every time: the compiler serializes the 128 per-k p4
// loads behind vmcnt(0) (minimum-register schedule), so every wave eats the
// full L2 latency 128 times. R12 proved named registers avoid scratch.
// Fix: explicit named-register double-buffer over p4 — q0..q7 current 8 rows,
// r0..r7 prefetch next 8 issued before the ~420cyc of STEP compute, then
// rename. No arrays, no LDS, no waitcnt pinning. x stays on the scalar path
// (row-major; xr_j[kb..kb+7] merges to s_load_dwordx8).

#define BM 32
#define BN 64
#define TM 8

// ---- prep: y (2048,256) -> p4[k][n] = {center, hd, inv, c2}, [128][2048] ----
__global__ __launch_bounds__(256) void boxe_prep(const float* __restrict__ y,
                                                 float4* __restrict__ p4)
{
    __shared__ float t0[128][9], t1[128][9], t2[128][9], t3[128][9];
    const int tid = threadIdx.x;
    const int n0  = blockIdx.x * 8;

    // phase 1: k-fastest mapping -> coalesced y reads (256B/wave)
#pragma unroll
    for (int i = 0; i < 4; ++i) {
        int j  = i * 256 + tid;        // 0..1023 = 8 n x 128 k
        int k  = j & 127;
        int nl = j >> 7;
        int n  = n0 + nl;
        float mn = y[n * 256 + k];
        float dv = y[n * 256 + 128 + k];
        // stable softplus: max(v,0) + log1p(exp(-|v|))  (matches jax.nn.softplus)
        float delta = fmaxf(dv, 0.0f) + log1pf(expf(-fabsf(dv)));
        float hd  = 0.5f * delta;
        t0[k][nl] = mn + hd;                                // center
        t1[k][nl] = hd;                                     // half-width
        t2[k][nl] = 1.0f / (delta + 1.0f + 1e-10f);         // 1/(dp1+eps)
        t3[k][nl] = hd * (delta - 1.0f / (delta + 1e-10f)); // c2
    }
    __syncthreads();

    // phase 2: n-fastest mapping -> coalesced p4 writes
#pragma unroll
    for (int i = 0; i < 4; ++i) {
        int j  = i * 256 + tid;
        int nl = j & 7;
        int k  = j >> 3;
        p4[k * 2048 + n0 + nl] =
            make_float4(t0[k][nl], t1[k][nl], t2[k][nl], t3[k][nl]);
    }
}

// ---- main: out[m][n] = -sqrt( sum_k per_dim^2 ) ----
// No LDS. Wave: 8 m-rows (x scalar path), 64 n (one per lane).
__global__ __launch_bounds__(256, 4) void boxe_main(
    const float4* __restrict__ p4, const float* __restrict__ x,
    float* __restrict__ out)
{
    const int tid  = threadIdx.x;
    const int lane = tid & 63;
    const int wave = __builtin_amdgcn_readfirstlane(tid >> 6);  // uniform
    const int m0   = blockIdx.y * BM + wave * TM;  // this wave's first m-row
    const int n    = blockIdx.x * BN + lane;       // one box per lane

    // Uniform row pointers -> x reads are scalar (s_load) from K$.
    const float* xr0 = x + (m0 + 0) * 128;
    const float* xr1 = x + (m0 + 1) * 128;
    const float* xr2 = x + (m0 + 2) * 128;
    const float* xr3 = x + (m0 + 3) * 128;
    const float* xr4 = x + (m0 + 4) * 128;
    const float* xr5 = x + (m0 + 5) * 128;
    const float* xr6 = x + (m0 + 6) * 128;
    const float* xr7 = x + (m0 + 7) * 128;

    const float4* pp = p4 + n;

    float acc0 = 0.0f, acc1 = 0.0f, acc2 = 0.0f, acc3 = 0.0f;
    float acc4 = 0.0f, acc5 = 0.0f, acc6 = 0.0f, acc7 = 0.0f;

    // One k-step: consume params P at k-row KK against the wave's 8 x-values.
#define STEP(P, KK)                                                        \
    do {                                                                   \
        float dp1 = fmaf(2.0f, (P).y, 1.0f);  /* delta+1, exact */         \
        float l0 = fabsf(xr0[(KK)] - (P).x);                               \
        float l1 = fabsf(xr1[(KK)] - (P).x);                               \
        float l2 = fabsf(xr2[(KK)] - (P).x);                               \
        float l3 = fabsf(xr3[(KK)] - (P).x);                               \
        float l4 = fabsf(xr4[(KK)] - (P).x);                               \
        float l5 = fabsf(xr5[(KK)] - (P).x);                               \
        float l6 = fabsf(xr6[(KK)] - (P).x);                               \
        float l7 = fabsf(xr7[(KK)] - (P).x);                               \
        float v0 = (l0 <= (P).y) ? (l0 * (P).z) : fmaf(l0, dp1, -(P).w);   \
        float v1 = (l1 <= (P).y) ? (l1 * (P).z) : fmaf(l1, dp1, -(P).w);   \
        float v2 = (l2 <= (P).y) ? (l2 * (P).z) : fmaf(l2, dp1, -(P).w);   \
        float v3 = (l3 <= (P).y) ? (l3 * (P).z) : fmaf(l3, dp1, -(P).w);   \
        float v4 = (l4 <= (P).y) ? (l4 * (P).z) : fmaf(l4, dp1, -(P).w);   \
        float v5 = (l5 <= (P).y) ? (l5 * (P).z) : fmaf(l5, dp1, -(P).w);   \
        float v6 = (l6 <= (P).y) ? (l6 * (P).z) : fmaf(l6, dp1, -(P).w);   \
        float v7 = (l7 <= (P).y) ? (l7 * (P).z) : fmaf(l7, dp1, -(P).w);   \
        acc0 = fmaf(v0, v0, acc0);                                         \
        acc1 = fmaf(v1, v1, acc1);                                         \
        acc2 = fmaf(v2, v2, acc2);                                         \
        acc3 = fmaf(v3, v3, acc3);                                         \
        acc4 = fmaf(v4, v4, acc4);                                         \
        acc5 = fmaf(v5, v5, acc5);                                         \
        acc6 = fmaf(v6, v6, acc6);                                         \
        acc7 = fmaf(v7, v7, acc7);                                         \
    } while (0)

    // Prologue: rows 0..7 live in named registers.
    float4 q0 = pp[0 * 2048];
    float4 q1 = pp[1 * 2048];
    float4 q2 = pp[2 * 2048];
    float4 q3 = pp[3 * 2048];
    float4 q4 = pp[4 * 2048];
    float4 q5 = pp[5 * 2048];
    float4 q6 = pp[6 * 2048];
    float4 q7 = pp[7 * 2048];

    // Steady state: prefetch next 8 rows, compute current 8, rename.
    int kb = 0;
    for (int it = 0; it < 15; ++it, kb += 8) {
        float4 r0 = pp[(kb +  8) * 2048];
        float4 r1 = pp[(kb +  9) * 2048];
        float4 r2 = pp[(kb + 10) * 2048];
        float4 r3 = pp[(kb + 11) * 2048];
        float4 r4 = pp[(kb + 12) * 2048];
        float4 r5 = pp[(kb + 13) * 2048];
        float4 r6 = pp[(kb + 14) * 2048];
        float4 r7 = pp[(kb + 15) * 2048];
        STEP(q0, kb + 0);
        STEP(q1, kb + 1);
        STEP(q2, kb + 2);
        STEP(q3, kb + 3);
        STEP(q4, kb + 4);
        STEP(q5, kb + 5);
        STEP(q6, kb + 6);
        STEP(q7, kb + 7);
        q0 = r0; q1 = r1; q2 = r2; q3 = r3;
        q4 = r4; q5 = r5; q6 = r6; q7 = r7;
    }
    // Epilogue: rows 120..127.
    STEP(q0, 120); STEP(q1, 121); STEP(q2, 122); STEP(q3, 123);
    STEP(q4, 124); STEP(q5, 125); STEP(q6, 126); STEP(q7, 127);
#undef STEP

    out[(m0 + 0) * 2048 + n] = -sqrtf(acc0);
    out[(m0 + 1) * 2048 + n] = -sqrtf(acc1);
    out[(m0 + 2) * 2048 + n] = -sqrtf(acc2);
    out[(m0 + 3) * 2048 + n] = -sqrtf(acc3);
    out[(m0 + 4) * 2048 + n] = -sqrtf(acc4);
    out[(m0 + 5) * 2048 + n] = -sqrtf(acc5);
    out[(m0 + 6) * 2048 + n] = -sqrtf(acc6);
    out[(m0 + 7) * 2048 + n] = -sqrtf(acc7);
}

extern "C" void kernel_launch(void* const* d_in, const int* in_sizes, int n_in,
                              void* d_out, int out_size, void* d_ws, size_t ws_size,
                              hipStream_t stream) {
    const float* y = (const float*)d_in[0];   // 2048*256
    const float* x = (const float*)d_in[1];   // 1024*128
    float* out = (float*)d_out;               // 1024*2048

    float4* p4 = (float4*)d_ws;               // 4 MiB: [128][2048] float4

    hipLaunchKernelGGL(boxe_prep, dim3(2048 / 8), dim3(256), 0, stream, y, p4);

    dim3 grid(2048 / BN, 1024 / BM);          // (32, 32) = 1024 blocks
    hipLaunchKernelGGL(boxe_main, grid, dim3(256), 0, stream, p4, x, out);
}